// Round 2
// baseline (231.949 us; speedup 1.0000x reference)
//
#include <hip/hip_runtime.h>
#include <hip/hip_bf16.h>
#include <stdint.h>

typedef unsigned short u16;
typedef __bf16 bf16x8 __attribute__((ext_vector_type(8)));
typedef float f32x4 __attribute__((ext_vector_type(4)));

#define MFMA16(a, b, c) __builtin_amdgcn_mfma_f32_16x16x32_bf16((a), (b), (c), 0, 0, 0)

#define GLOAD16(g, l)                                                        \
  __builtin_amdgcn_global_load_lds(                                          \
      (const __attribute__((address_space(1))) void*)(g),                    \
      (__attribute__((address_space(3))) void*)(l), 16, 0, 0)

static __device__ __forceinline__ u16 f2bf(float f) {
  union { float f; uint32_t u; } v;
  v.f = f;
  uint32_t u = v.u;
  return (u16)((u + 0x7FFFu + ((u >> 16) & 1u)) >> 16);  // RNE
}

// ---- workspace layout (u16 elements) ----
#define FEATT_ELEMS (8u * 98u * 98u * 256u)   // [b][h+1][w+1][c] bf16, zero halo
#define W1T_OFF     FEATT_ELEMS               // [oc][tap][cin] bf16: 256*2304
#define W1T_ELEMS   (256u * 2304u)
#define W2B_OFF     (W1T_OFF + W1T_ELEMS)     // [576][256] bf16
#define W2B_ELEMS   (576u * 256u)
#define X_OFF       (W2B_OFF + W2B_ELEMS)     // [73728][256] bf16

// ---------------- halo zeroing (replaces 39MB memset; halo is 1.6MB) ------------
__global__ __launch_bounds__(256) void halo_zero(u16* __restrict__ featT) {
  int tid = blockIdx.x * 256 + threadIdx.x;  // 8 * 388 * 32 = 99328 threads
  int b = tid / (388 * 32);
  int rem = tid % (388 * 32);
  int pos = rem >> 5, v = rem & 31;
  int h, w;
  if (pos < 98) { h = 0; w = pos; }
  else if (pos < 196) { h = 97; w = pos - 98; }
  else if (pos < 292) { h = pos - 196 + 1; w = 0; }
  else { h = pos - 292 + 1; w = 97; }
  uint4* dst = (uint4*)(featT + (size_t)((b * 98 + h) * 98 + w) * 256 + v * 8);
  *dst = make_uint4(0, 0, 0, 0);
}

// ---------------- prep: feat NCHW f32 -> featT [b][h+1][w+1][c] bf16 -------------
__global__ __launch_bounds__(256) void prep_featT(const float* __restrict__ feat,
                                                  u16* __restrict__ featT) {
  const int pt = blockIdx.x, ct = blockIdx.y, b = blockIdx.z;
  const int p0 = pt * 64, c0 = ct * 64;
  __shared__ float tile[64][65];
  const int t = threadIdx.x;
  const int pj = t & 63, ci0 = t >> 6;
#pragma unroll
  for (int r = 0; r < 16; ++r) {
    int ci = r * 4 + ci0;
    tile[ci][pj] = feat[(b * 256 + c0 + ci) * 9216 + p0 + pj];
  }
  __syncthreads();
  const int pl = t >> 2, cc0 = (t & 3) * 16;
  const int pix = p0 + pl;
  const int h = pix / 96, w = pix % 96;
  uint32_t u[8];
#pragma unroll
  for (int i = 0; i < 8; ++i) {
    u16 lo = f2bf(tile[cc0 + 2 * i][pl]);
    u16 hi = f2bf(tile[cc0 + 2 * i + 1][pl]);
    u[i] = (uint32_t)lo | ((uint32_t)hi << 16);
  }
  uint4* dst = (uint4*)(featT + (size_t)((b * 98 + h + 1) * 98 + (w + 1)) * 256 + c0 + cc0);
  dst[0] = make_uint4(u[0], u[1], u[2], u[3]);
  dst[1] = make_uint4(u[4], u[5], u[6], u[7]);
}

// ---------------- prep: weights -> bf16 (w1 reordered to [oc][tap][cin]) ---------
__global__ __launch_bounds__(256) void prep_w(const float* __restrict__ w1,
                                              const float* __restrict__ w2,
                                              u16* __restrict__ w1t,
                                              u16* __restrict__ w2b) {
  int i = blockIdx.x * 256 + threadIdx.x;
  if (i < 589824) {
    int oc = i / 2304, r = i % 2304;
    int tap = r >> 8, cin = r & 255;
    w1t[i] = f2bf(w1[(oc * 256 + cin) * 9 + tap]);
  } else {
    int j = i - 589824;
    if (j < 147456) w2b[j] = f2bf(w2[j]);
  }
}

// ---------------- GEMM1: x[pix][oc] = conv3x3(feat) + b1, relu, bf16 -------------
// M=73728, N=256 (single tile), K=2304. BM=128, BN=256, BK=64, 8 waves (2M x 4N).
// Single-buffered LDS (48KB) -> 2 blocks/CU, 4 waves/SIMD (m97 structure).
__global__ __launch_bounds__(512, 4) void gemm1(const u16* __restrict__ featT,
                                                const u16* __restrict__ w1t,
                                                const float* __restrict__ b1,
                                                u16* __restrict__ xout) {
  __shared__ __align__(16) u16 sA[128 * 64];  // 16KB
  __shared__ __align__(16) u16 sB[256 * 64];  // 32KB
  __shared__ float sb1[256];

  const int t = threadIdx.x;
  const int wave = t >> 6, lane = t & 63;
  const int mt = blockIdx.x;
  const int b = mt / 72;
  const int ip0 = (mt % 72) * 128;

  if (t < 256) sb1[t] = b1[t];

  // staging bases: each wave instr covers 8 rows (1KB LDS), lane -> (row, chunk)
  const u16* aBase[2];
  const u16* bBase[4];
#pragma unroll
  for (int r = 0; r < 2; ++r) {
    int row = r * 64 + wave * 8 + (lane >> 3);  // 0..127
    int chunk = (lane & 7) ^ (row & 7);
    int ip = ip0 + row;
    int h = ip / 96, w = ip % 96;
    aBase[r] = featT + (size_t)((b * 98 + h + 1) * 98 + (w + 1)) * 256 + chunk * 8;
  }
#pragma unroll
  for (int r = 0; r < 4; ++r) {
    int row = wave * 32 + r * 8 + (lane >> 3);  // 0..255
    int chunk = (lane & 7) ^ (row & 7);
    bBase[r] = w1t + (size_t)row * 2304 + chunk * 8;
  }

  const int wm = wave >> 2, wn = wave & 3;
  int aoffs[4][2], boffs[4][2];
#pragma unroll
  for (int m = 0; m < 4; ++m) {
#pragma unroll
    for (int ki = 0; ki < 2; ++ki) {
      int kc = ki * 4 + (lane >> 4);
      int rowa = wm * 64 + m * 16 + (lane & 15);
      aoffs[m][ki] = rowa * 64 + ((kc ^ (rowa & 7)) * 8);
      int rowb = wn * 64 + m * 16 + (lane & 15);
      boffs[m][ki] = rowb * 64 + ((kc ^ (rowb & 7)) * 8);
    }
  }

  f32x4 acc[4][4];
#pragma unroll
  for (int m = 0; m < 4; ++m)
#pragma unroll
    for (int n = 0; n < 4; ++n) acc[m][n] = f32x4{0.f, 0.f, 0.f, 0.f};

  for (int kt = 0; kt < 36; ++kt) {
    int tap = kt >> 2;
    int dh = tap / 3 - 1, dw = tap % 3 - 1;
    int aoff = (dh * 98 + dw) * 256 + (kt & 3) * 64;
    int boff = kt * 64;
#pragma unroll
    for (int r = 0; r < 2; ++r) GLOAD16(aBase[r] + aoff, &sA[(r * 64 + wave * 8) * 64]);
#pragma unroll
    for (int r = 0; r < 4; ++r) GLOAD16(bBase[r] + boff, &sB[(wave * 32 + r * 8) * 64]);
    __syncthreads();  // vmcnt(0) drain + barrier: tile ready
#pragma unroll
    for (int ki = 0; ki < 2; ++ki) {
      bf16x8 av[4], bv[4];
#pragma unroll
      for (int m = 0; m < 4; ++m) av[m] = *(const bf16x8*)&sA[aoffs[m][ki]];
#pragma unroll
      for (int n = 0; n < 4; ++n) bv[n] = *(const bf16x8*)&sB[boffs[n][ki]];
#pragma unroll
      for (int m = 0; m < 4; ++m)
#pragma unroll
        for (int n = 0; n < 4; ++n) acc[m][n] = MFMA16(av[m], bv[n], acc[m][n]);
    }
    __syncthreads();  // all reads done before next stage overwrites
  }

  const int pix0g = mt * 128;
#pragma unroll
  for (int m = 0; m < 4; ++m) {
    int pixl = wm * 64 + m * 16 + ((lane >> 4) << 2);
#pragma unroll
    for (int n = 0; n < 4; ++n) {
      int oc = wn * 64 + n * 16 + (lane & 15);
      float bias = sb1[oc];
      f32x4 v = acc[m][n];
#pragma unroll
      for (int j = 0; j < 4; ++j) {
        float val = v[j] + bias;
        val = val > 0.f ? val : 0.f;
        xout[(size_t)(pix0g + pixl + j) * 256 + oc] = f2bf(val);
      }
    }
  }
}

// ------- GEMM2: mask = x @ w2^T (+b2), softmax over 9, combine flow, scatter -----
// A-fragments hoisted to registers (16 VGPR/lane); the 64KB sX region is then
// reused for the B double-buffer -> LDS 75.5KB -> 2 blocks/CU.
__global__ __launch_bounds__(512, 4) void gemm2(const u16* __restrict__ xws,
                                                const u16* __restrict__ w2b,
                                                const float* __restrict__ b2,
                                                const float* __restrict__ flow,
                                                float* __restrict__ out) {
  __shared__ __align__(16) u16 smem0[128 * 256];  // 64KB: sX, then sB2[2][144*64]
  __shared__ float sFlow[2][9][128];
  __shared__ float sb2[576];

  const int t = threadIdx.x;
  const int wave = t >> 6, lane = t & 63;
  const int mt = blockIdx.x;
  const int b = mt / 72;
  const int ip0 = (mt % 72) * 128;

  // stage x tile (source-chunk swizzled)
#pragma unroll
  for (int r = 0; r < 8; ++r) {
    int wr = r * 8 + wave;           // 0..63
    int pix = wr * 2 + (lane >> 5);  // 0..127
    int cpos = lane & 31;
    const u16* src = xws + (size_t)(mt * 128 + pix) * 256 + ((cpos ^ (pix & 7)) * 8);
    GLOAD16(src, &smem0[wr * 512]);
  }
  // flow-unfold tile: sFlow[c][k][p]
  for (int i = t; i < 2304; i += 512) {
    int c = i / 1152, rem = i % 1152;
    int k = rem >> 7, p = rem & 127;
    int ip = ip0 + p;
    int h = ip / 96, w = ip % 96;
    int hh = h + k / 3 - 1, ww = w + k % 3 - 1;
    float v = 0.f;
    if (hh >= 0 && hh < 96 && ww >= 0 && ww < 96)
      v = flow[((b * 2 + c) * 96 + hh) * 96 + ww];
    sFlow[c][k][p] = v;
  }
  for (int i = t; i < 576; i += 512) sb2[i] = b2[i];
  __syncthreads();

  // extract this wave's A fragments into registers (full K=256 for its 16 pixels)
  const int pixl = wave * 16 + (lane & 15);
  bf16x8 areg[8];
#pragma unroll
  for (int s = 0; s < 8; ++s) {
    int kc = s * 4 + (lane >> 4);
    areg[s] = *(const bf16x8*)&smem0[pixl * 256 + ((kc ^ (pixl & 7)) * 8)];
  }
  __syncthreads();  // everyone done with sX; region becomes sB2

  auto stageB = [&](int step, int bufi) {
    int chunkI = step >> 2, ks = step & 3;
#pragma unroll
    for (int r = 0; r < 3; ++r) {
      int wr = r * 8 + wave;  // wave-uniform condition
      if (wr < 18) {
        int row = wr * 8 + (lane >> 3);  // virtual n, 0..143
        int c = (row >> 4) * 64 + chunkI * 16 + (row & 15);
        const u16* src = w2b + (size_t)c * 256 + ks * 64 + (((lane & 7) ^ (row & 7)) * 8);
        GLOAD16(src, &smem0[bufi * 9216 + wr * 512]);
      }
    }
  };

  stageB(0, 0);
  f32x4 acc[9];
#pragma unroll
  for (int nf = 0; nf < 9; ++nf) acc[nf] = f32x4{0.f, 0.f, 0.f, 0.f};

#pragma unroll
  for (int step = 0; step < 16; ++step) {
    __syncthreads();
    if (step < 15) stageB(step + 1, (step & 1) ^ 1);
    const int buf = step & 1;
    const int ks = step & 3;
#pragma unroll
    for (int ki = 0; ki < 2; ++ki) {
      int kc = ki * 4 + (lane >> 4);
      bf16x8 a = areg[ks * 2 + ki];  // static (step loop fully unrolled)
#pragma unroll
      for (int nf = 0; nf < 9; ++nf) {
        int row = nf * 16 + (lane & 15);
        bf16x8 bv = *(const bf16x8*)&smem0[buf * 9216 + row * 64 + ((kc ^ (row & 7)) * 8)];
        acc[nf] = MFMA16(a, bv, acc[nf]);
      }
    }
    if (ks == 3) {
      int chunkI = step >> 2;
      int pql = lane & 15;
      int p = chunkI * 2 + (pql >> 3), q = pql & 7;
#pragma unroll
      for (int j = 0; j < 4; ++j) {
        int pe = wave * 16 + ((lane >> 4) << 2) + j;
        float v[9], mx = -3.0e38f;
#pragma unroll
        for (int nf = 0; nf < 9; ++nf) {
          v[nf] = acc[nf][j] + sb2[nf * 64 + chunkI * 16 + pql];
          mx = fmaxf(mx, v[nf]);
        }
        float s = 0.f, fx = 0.f, fy = 0.f;
#pragma unroll
        for (int nf = 0; nf < 9; ++nf) {
          float e = __expf(v[nf] - mx);
          s += e;
          fx += e * sFlow[0][nf][pe];
          fy += e * sFlow[1][nf][pe];
        }
        float sc = 8.0f / s;
        int ip = ip0 + pe;
        int h = ip / 96, w = ip % 96;
        size_t o0 = ((size_t)(b * 2 + 0) * 768 + h * 8 + p) * 768 + w * 8 + q;
        size_t o1 = ((size_t)(b * 2 + 1) * 768 + h * 8 + p) * 768 + w * 8 + q;
        out[o0] = fx * sc;
        out[o1] = fy * sc;
      }
#pragma unroll
      for (int nf = 0; nf < 9; ++nf) acc[nf] = f32x4{0.f, 0.f, 0.f, 0.f};
    }
  }
}

extern "C" void kernel_launch(void* const* d_in, const int* in_sizes, int n_in,
                              void* d_out, int out_size, void* d_ws, size_t ws_size,
                              hipStream_t stream) {
  const float* flow = (const float*)d_in[0];
  const float* feat = (const float*)d_in[1];
  const float* w1 = (const float*)d_in[2];
  const float* b1 = (const float*)d_in[3];
  const float* w2 = (const float*)d_in[4];
  const float* b2 = (const float*)d_in[5];
  float* out = (float*)d_out;
  u16* ws = (u16*)d_ws;
  u16* featT = ws;
  u16* w1t = ws + W1T_OFF;
  u16* w2b = ws + W2B_OFF;
  u16* xws = ws + X_OFF;

  halo_zero<<<388, 256, 0, stream>>>(featT);
  prep_featT<<<dim3(144, 4, 8), 256, 0, stream>>>(feat, featT);
  prep_w<<<2880, 256, 0, stream>>>(w1, w2, w1t, w2b);
  gemm1<<<576, 512, 0, stream>>>(featT, w1t, b1, xws);
  gemm2<<<576, 512, 0, stream>>>(xws, w2b, b2, flow, out);
}

// Round 3
// 201.962 us; speedup vs baseline: 1.1485x; 1.1485x over previous
//
#include <hip/hip_runtime.h>
#include <hip/hip_bf16.h>
#include <stdint.h>

typedef unsigned short u16;
typedef __bf16 bf16x8 __attribute__((ext_vector_type(8)));
typedef float f32x4 __attribute__((ext_vector_type(4)));

#define MFMA16(a, b, c) __builtin_amdgcn_mfma_f32_16x16x32_bf16((a), (b), (c), 0, 0, 0)

#define GLOAD16(g, l)                                                        \
  __builtin_amdgcn_global_load_lds(                                          \
      (const __attribute__((address_space(1))) void*)(g),                    \
      (__attribute__((address_space(3))) void*)(l), 16, 0, 0)

static __device__ __forceinline__ u16 f2bf(float f) {
  union { float f; uint32_t u; } v;
  v.f = f;
  uint32_t u = v.u;
  return (u16)((u + 0x7FFFu + ((u >> 16) & 1u)) >> 16);  // RNE
}

// ---- workspace layout (u16 elements) ----
#define FEATT_ELEMS (8u * 98u * 98u * 256u)   // [b][h+1][w+1][c] bf16, zero halo
#define W1T_OFF     FEATT_ELEMS               // [oc][tap][cin] bf16: 256*2304
#define W1T_ELEMS   (256u * 2304u)
#define W2B_OFF     (W1T_OFF + W1T_ELEMS)     // [576][256] bf16

// ---------------- halo zeroing (halo is 1.6MB) ------------
__global__ __launch_bounds__(256) void halo_zero(u16* __restrict__ featT) {
  int tid = blockIdx.x * 256 + threadIdx.x;  // 8 * 388 * 32 = 99328 threads
  int b = tid / (388 * 32);
  int rem = tid % (388 * 32);
  int pos = rem >> 5, v = rem & 31;
  int h, w;
  if (pos < 98) { h = 0; w = pos; }
  else if (pos < 196) { h = 97; w = pos - 98; }
  else if (pos < 292) { h = pos - 196 + 1; w = 0; }
  else { h = pos - 292 + 1; w = 97; }
  uint4* dst = (uint4*)(featT + (size_t)((b * 98 + h) * 98 + w) * 256 + v * 8);
  *dst = make_uint4(0, 0, 0, 0);
}

// ---------------- prep: feat NCHW f32 -> featT [b][h+1][w+1][c] bf16 -------------
__global__ __launch_bounds__(256) void prep_featT(const float* __restrict__ feat,
                                                  u16* __restrict__ featT) {
  const int pt = blockIdx.x, ct = blockIdx.y, b = blockIdx.z;
  const int p0 = pt * 64, c0 = ct * 64;
  __shared__ float tile[64][65];
  const int t = threadIdx.x;
  const int pj = t & 63, ci0 = t >> 6;
#pragma unroll
  for (int r = 0; r < 16; ++r) {
    int ci = r * 4 + ci0;
    tile[ci][pj] = feat[(b * 256 + c0 + ci) * 9216 + p0 + pj];
  }
  __syncthreads();
  const int pl = t >> 2, cc0 = (t & 3) * 16;
  const int pix = p0 + pl;
  const int h = pix / 96, w = pix % 96;
  uint32_t u[8];
#pragma unroll
  for (int i = 0; i < 8; ++i) {
    u16 lo = f2bf(tile[cc0 + 2 * i][pl]);
    u16 hi = f2bf(tile[cc0 + 2 * i + 1][pl]);
    u[i] = (uint32_t)lo | ((uint32_t)hi << 16);
  }
  uint4* dst = (uint4*)(featT + (size_t)((b * 98 + h + 1) * 98 + (w + 1)) * 256 + c0 + cc0);
  dst[0] = make_uint4(u[0], u[1], u[2], u[3]);
  dst[1] = make_uint4(u[4], u[5], u[6], u[7]);
}

// ---------------- prep: weights -> bf16 (w1 reordered to [oc][tap][cin]) ---------
__global__ __launch_bounds__(256) void prep_w(const float* __restrict__ w1,
                                              const float* __restrict__ w2,
                                              u16* __restrict__ w1t,
                                              u16* __restrict__ w2b) {
  int i = blockIdx.x * 256 + threadIdx.x;
  if (i < 589824) {
    int oc = i / 2304, r = i % 2304;
    int tap = r >> 8, cin = r & 255;
    w1t[i] = f2bf(w1[(oc * 256 + cin) * 9 + tap]);
  } else {
    int j = i - 589824;
    if (j < 147456) w2b[j] = f2bf(w2[j]);
  }
}

// =================== FUSED: conv3x3+relu -> 1x1 -> softmax -> combine ===========
// Tile = one image row: 96 pixels (BM=96), full N=256. 768 blocks = 3/CU exact.
// Phase A: GEMM M=96,N=256,K=2304; 2-phase prefetch, 1 barrier/K-step.
// Handoff: x-tile (96x256 bf16, 48KB) via LDS, A-frags -> registers.
// Phase C: mask GEMM (N_virt=576) + softmax + flow-combine + pixel-shuffle store.
__global__ __launch_bounds__(512, 2) void fused(const u16* __restrict__ featT,
                                                const u16* __restrict__ w1t,
                                                const float* __restrict__ b1,
                                                const u16* __restrict__ w2b,
                                                const float* __restrict__ b2,
                                                const float* __restrict__ flow,
                                                float* __restrict__ out) {
  // [0,45056): phase A dbuf (2 x (sA 6144 + sB 16384))
  // [0,24576): sX handoff (96x256)    [24576,61440): phase C B dbuf (2 x 18432)
  __shared__ __align__(16) u16 smem[61440];      // 120 KB
  __shared__ float sFlow[2][9][96];              // 6.75 KB
  __shared__ float sb1[256];
  __shared__ float sb2[576];

  const int t = threadIdx.x;
  const int wave = t >> 6, lane = t & 63;
  const int bid = blockIdx.x;
  const int mt = (bid & 7) * 96 + (bid >> 3);    // bijective XCD swizzle (768%8==0)
  const int b = mt / 96;
  const int h0 = mt % 96;                        // this block = image row h0

  if (t < 256) sb1[t] = b1[t];
  for (int i = t; i < 576; i += 512) sb2[i] = b2[i];
  for (int i = t; i < 1728; i += 512) {
    int c = i / 864, rem = i % 864;
    int k = rem / 96, p = rem % 96;
    int hh = h0 + k / 3 - 1, ww = p + k % 3 - 1;
    float v = 0.f;
    if (hh >= 0 && hh < 96 && ww >= 0 && ww < 96)
      v = flow[((b * 2 + c) * 96 + hh) * 96 + ww];
    sFlow[c][k][p] = v;
  }

  // ---- phase A staging bases (source pre-swizzled chunks) ----
  const u16* aBase[2];
#pragma unroll
  for (int r = 0; r < 2; ++r) {
    int row = (r * 8 + wave) * 8 + (lane >> 3);  // w-coordinate, 0..95 (wr<12 valid)
    int chunk = (lane & 7) ^ (row & 7);
    aBase[r] = featT + ((size_t)(b * 98 + h0 + 1) * 98 + (row + 1)) * 256 + chunk * 8;
  }
  const u16* bBase[4];
#pragma unroll
  for (int r = 0; r < 4; ++r) {
    int row = (r * 8 + wave) * 8 + (lane >> 3);  // oc, 0..255
    int chunk = (lane & 7) ^ (row & 7);
    bBase[r] = w1t + (size_t)row * 2304 + chunk * 8;
  }

  auto stageA = [&](int kt, int bufi) {
    int tap = kt >> 2;
    int dh = tap / 3 - 1, dw = tap % 3 - 1;
    int aoff = (dh * 98 + dw) * 256 + (kt & 3) * 64;
    int boff = kt * 64;
    u16* base = &smem[bufi * 22528];
#pragma unroll
    for (int r = 0; r < 2; ++r) {
      int wr = r * 8 + wave;
      if (wr < 12) GLOAD16(aBase[r] + aoff, base + wr * 512);
    }
#pragma unroll
    for (int r = 0; r < 4; ++r)
      GLOAD16(bBase[r] + boff, base + 6144 + (r * 8 + wave) * 512);
  };

  const int wm = wave >> 2, wn = wave & 3;
  int aoffs[3][2], boffs[4][2];
#pragma unroll
  for (int ki = 0; ki < 2; ++ki) {
    int kc = ki * 4 + (lane >> 4);
#pragma unroll
    for (int m = 0; m < 3; ++m) {
      int rowa = wm * 48 + m * 16 + (lane & 15);
      aoffs[m][ki] = rowa * 64 + ((kc ^ (rowa & 7)) * 8);
    }
#pragma unroll
    for (int n = 0; n < 4; ++n) {
      int rowb = wn * 64 + n * 16 + (lane & 15);
      boffs[n][ki] = rowb * 64 + ((kc ^ (rowb & 7)) * 8);
    }
  }

  f32x4 acc[3][4];
#pragma unroll
  for (int m = 0; m < 3; ++m)
#pragma unroll
    for (int n = 0; n < 4; ++n) acc[m][n] = f32x4{0.f, 0.f, 0.f, 0.f};

  stageA(0, 0);
  __syncthreads();
  int buf = 0;
  for (int kt = 0; kt < 36; ++kt) {
    if (kt < 35) stageA(kt + 1, buf ^ 1);  // prefetch overlaps this tile's MFMAs
    const u16* base = &smem[buf * 22528];
#pragma unroll
    for (int ki = 0; ki < 2; ++ki) {
      bf16x8 av[3], bv[4];
#pragma unroll
      for (int m = 0; m < 3; ++m) av[m] = *(const bf16x8*)&base[aoffs[m][ki]];
#pragma unroll
      for (int n = 0; n < 4; ++n) bv[n] = *(const bf16x8*)&base[6144 + boffs[n][ki]];
#pragma unroll
      for (int m = 0; m < 3; ++m)
#pragma unroll
        for (int n = 0; n < 4; ++n) acc[m][n] = MFMA16(av[m], bv[n], acc[m][n]);
    }
    __syncthreads();  // == vmcnt(0)+lgkmcnt(0)+barrier: prefetch landed, reads done
    buf ^= 1;
  }

  // ---- phase A epilogue: bias+relu -> sX[pix][oc] (chunk-swizzled) ----
  const int g4 = (lane >> 4) << 2;
#pragma unroll
  for (int m = 0; m < 3; ++m) {
    int pixr = wm * 48 + m * 16 + g4;
#pragma unroll
    for (int n = 0; n < 4; ++n) {
      int oc = wn * 64 + n * 16 + (lane & 15);
      float bias = sb1[oc];
      f32x4 v = acc[m][n];
#pragma unroll
      for (int j = 0; j < 4; ++j) {
        int pix = pixr + j;
        float val = v[j] + bias;
        val = val > 0.f ? val : 0.f;
        smem[pix * 256 + (((oc >> 3) ^ (pix & 7)) * 8) + (oc & 7)] = f2bf(val);
      }
    }
  }
  __syncthreads();  // sX complete

  // ---- phase C: B2 staging + A-frag extraction ----
  auto stageB = [&](int step, int bufi) {
    int cI = step >> 1, kh = step & 1;
    u16* base = &smem[24576 + bufi * 18432];
#pragma unroll
    for (int r = 0; r < 5; ++r) {
      int wr = r * 8 + wave;
      if (wr < 36) {
        int row = wr * 4 + (lane >> 4);  // virtual n, 0..143
        int chan = (row >> 4) * 64 + cI * 16 + (row & 15);
        int c = lane & 15;
        const u16* src = w2b + (size_t)chan * 256 + kh * 128 + ((c ^ (row & 15)) * 8);
        GLOAD16(src, base + wr * 512);
      }
    }
  };

  stageB(0, 0);  // writes [24576,...): no overlap with sX reads below
  bf16x8 areg[8];
  const int pixl = wave * 16 + (lane & 15);  // valid for wave<6
  if (wave < 6) {
#pragma unroll
    for (int s = 0; s < 8; ++s) {
      int kc = s * 4 + (lane >> 4);  // oc chunk 0..31
      areg[s] = *(const bf16x8*)&smem[pixl * 256 + ((kc ^ (pixl & 7)) * 8)];
    }
  }
  __syncthreads();  // stage(0) drained + extraction done

  f32x4 acc2[9];
  int bufc = 0;
#pragma unroll
  for (int step = 0; step < 8; ++step) {
    if (step < 7) stageB(step + 1, bufc ^ 1);
    const int kh = step & 1, cI = step >> 1;
    if (wave < 6) {
      if (kh == 0) {
#pragma unroll
        for (int nf = 0; nf < 9; ++nf) acc2[nf] = f32x4{0.f, 0.f, 0.f, 0.f};
      }
      const u16* base = &smem[24576 + bufc * 18432];
#pragma unroll
      for (int ki = 0; ki < 4; ++ki) {
        bf16x8 a = areg[kh * 4 + ki];
        int kc = ki * 4 + (lane >> 4);
#pragma unroll
        for (int nf = 0; nf < 9; ++nf) {
          int row = nf * 16 + (lane & 15);
          bf16x8 bv = *(const bf16x8*)&base[row * 128 + ((kc ^ (row & 15)) * 8)];
          acc2[nf] = MFMA16(a, bv, acc2[nf]);
        }
      }
      if (kh == 1) {
        int pql = lane & 15;
        int p = cI * 2 + (pql >> 3), q = pql & 7;
#pragma unroll
        for (int j = 0; j < 4; ++j) {
          int pe = wave * 16 + g4 + j;  // w-coordinate, 0..95
          float v[9], mx = -3.0e38f;
#pragma unroll
          for (int nf = 0; nf < 9; ++nf) {
            v[nf] = acc2[nf][j] + sb2[nf * 64 + cI * 16 + pql];
            mx = fmaxf(mx, v[nf]);
          }
          float s = 0.f, fx = 0.f, fy = 0.f;
#pragma unroll
          for (int nf = 0; nf < 9; ++nf) {
            float e = __expf(v[nf] - mx);
            s += e;
            fx += e * sFlow[0][nf][pe];
            fy += e * sFlow[1][nf][pe];
          }
          float sc = 8.0f / s;
          size_t o0 = ((size_t)(b * 2 + 0) * 768 + h0 * 8 + p) * 768 + pe * 8 + q;
          size_t o1 = ((size_t)(b * 2 + 1) * 768 + h0 * 8 + p) * 768 + pe * 8 + q;
          out[o0] = fx * sc;
          out[o1] = fy * sc;
        }
      }
    }
    __syncthreads();
    bufc ^= 1;
  }
}

extern "C" void kernel_launch(void* const* d_in, const int* in_sizes, int n_in,
                              void* d_out, int out_size, void* d_ws, size_t ws_size,
                              hipStream_t stream) {
  const float* flow = (const float*)d_in[0];
  const float* feat = (const float*)d_in[1];
  const float* w1 = (const float*)d_in[2];
  const float* b1 = (const float*)d_in[3];
  const float* w2 = (const float*)d_in[4];
  const float* b2 = (const float*)d_in[5];
  float* out = (float*)d_out;
  u16* ws = (u16*)d_ws;
  u16* featT = ws;
  u16* w1t = ws + W1T_OFF;
  u16* w2b = ws + W2B_OFF;

  halo_zero<<<388, 256, 0, stream>>>(featT);
  prep_featT<<<dim3(144, 4, 8), 256, 0, stream>>>(feat, featT);
  prep_w<<<2880, 256, 0, stream>>>(w1, w2, w1t, w2b);
  fused<<<768, 512, 0, stream>>>(featT, w1t, b1, w2b, b2, flow, out);
}